// Round 1
// baseline (697.487 us; speedup 1.0000x reference)
//
#include <hip/hip_runtime.h>
#include <cstdint>
#include <cstddef>

// ---------------- problem constants ----------------
#define NTOK 16384          // 8*2048 tokens
#define DIM  512
#define KCB  8192           // codebook entries
#define MARGIN 4.5e-3f      // > worst-case bf16 screening error (2*2^-9 + slack)

typedef short s16x8 __attribute__((ext_vector_type(8)));   // 8 bf16 in 4 VGPRs
typedef float f32x4 __attribute__((ext_vector_type(4)));

// ---------------- workspace layout (bytes) ----------------
static const size_t WS_XN  = 0;                  // ushort[NTOK*DIM]      bf16 normalized x
static const size_t WS_WN  = 16777216;           // ushort[KCB*DIM]       bf16 normalized w
static const size_t WS_RV1 = 25165824;           // float[128*NTOK]       per-(tile64,token) top1
static const size_t WS_RV2 = 33554432;           // float[128*NTOK]       top2
static const size_t WS_RI1 = 41943040;           // int  [128*NTOK]       top1 code id
static const size_t WS_IDX = 50331648;           // int  [NTOK]
static const size_t WS_LP  = 50397184;           // float[32768]          loss partials
static const size_t WS_PRE = 50528256;           // float[KCB]            pre-smoothing cs
static const size_t WS_N   = 50561024;           // double                n = sum(new_cs)
static const size_t WS_DW  = 50561280;           // float[KCB*DIM]        scatter accumulator (zeroed)
static const size_t WS_CNT = 67338496;           // float[KCB]            counts (zeroed)
static const size_t WS_END = 67371264;

// ---------------- helpers ----------------
__device__ __forceinline__ void gl_lds16(const void* g, void* l) {
  // async 16B global->LDS; LDS dest is wave-uniform base + lane*16
  __builtin_amdgcn_global_load_lds(
      (__attribute__((address_space(1))) void*)(uintptr_t)g,
      (__attribute__((address_space(3))) void*)(uint32_t)(uintptr_t)l,
      16, 0, 0);
}

__device__ __forceinline__ unsigned short f2bf(float f) {
  unsigned int u = __float_as_uint(f);
  u = (u + 0x7fffu + ((u >> 16) & 1u)) >> 16;   // RNE
  return (unsigned short)u;
}

// ---------------- K1: l2-normalize x and w rows into bf16 ----------------
__global__ __launch_bounds__(256) void k_normalize(const float* __restrict__ x,
                                                   const float* __restrict__ w,
                                                   unsigned short* __restrict__ xn,
                                                   unsigned short* __restrict__ wn) {
  const int row = blockIdx.x;
  const int tid = threadIdx.x, lane = tid & 63, wave = tid >> 6;
  const float* src;
  unsigned short* dst;
  if (row < NTOK) { src = x + (size_t)row * DIM;          dst = xn + (size_t)row * DIM; }
  else            { src = w + (size_t)(row - NTOK) * DIM; dst = wn + (size_t)(row - NTOK) * DIM; }
  const int e = tid * 2;
  float2 v = *(const float2*)(src + e);
  float ss = v.x * v.x + v.y * v.y;
  #pragma unroll
  for (int off = 32; off > 0; off >>= 1) ss += __shfl_xor(ss, off);
  __shared__ float red[4];
  if (lane == 0) red[wave] = ss;
  __syncthreads();
  const float s = red[0] + red[1] + red[2] + red[3];
  const float inv = rsqrtf(s + 1e-12f);
  unsigned int lo = f2bf(v.x * inv), hi = f2bf(v.y * inv);
  *(unsigned int*)(dst + e) = lo | (hi << 16);
}

// ---------------- K2: bf16 MFMA GEMM (128x128 tile, BK=64) + top2 epilogue ----------------
// grid: (64 n-tiles, 128 m-tiles); block 256 = 4 waves in 2x2 arrangement
__global__ __launch_bounds__(256) void k_gemm_top2(const unsigned short* __restrict__ xn,
                                                   const unsigned short* __restrict__ wn,
                                                   float* __restrict__ rv1,
                                                   float* __restrict__ rv2,
                                                   int* __restrict__ ri1) {
  __shared__ __align__(16) unsigned short smA[128 * 64];
  __shared__ __align__(16) unsigned short smB[128 * 64];
  const int tid = threadIdx.x, wave = tid >> 6, lane = tid & 63;
  const int quad = lane >> 4, col = lane & 15;
  const int wave_m = (wave & 1) * 64, wave_n = (wave >> 1) * 64;
  const int n0 = blockIdx.x * 128, m0 = blockIdx.y * 128;

  f32x4 acc[4][4] = {};

  #pragma unroll 1
  for (int kt = 0; kt < 8; ++kt) {
    __syncthreads();                       // everyone done reading previous tiles
    const int kb0 = kt * 64;
    #pragma unroll
    for (int i = 0; i < 4; ++i) {          // A-tile: 1024 granules of 16B, swizzled
      int s = wave * 256 + i * 64 + lane;
      int row = s >> 3, cg = (s & 7) ^ (row & 7);
      gl_lds16(xn + (size_t)(m0 + row) * DIM + kb0 + cg * 8,
               &smA[(size_t)(wave * 256 + i * 64) * 8]);
    }
    #pragma unroll
    for (int i = 0; i < 4; ++i) {          // B-tile
      int s = wave * 256 + i * 64 + lane;
      int row = s >> 3, cg = (s & 7) ^ (row & 7);
      gl_lds16(wn + (size_t)(n0 + row) * DIM + kb0 + cg * 8,
               &smB[(size_t)(wave * 256 + i * 64) * 8]);
    }
    __syncthreads();                       // drains vmcnt before barrier
    #pragma unroll
    for (int kk = 0; kk < 2; ++kk) {
      const int kb = kk * 4 + quad;        // logical 8-elem granule index in BK=64
      s16x8 af[4], bf[4];
      #pragma unroll
      for (int mi = 0; mi < 4; ++mi) {
        int row = wave_m + mi * 16 + col;
        int g = row * 8 + (kb ^ (row & 7));
        af[mi] = *(const s16x8*)&smA[g * 8];
      }
      #pragma unroll
      for (int ni = 0; ni < 4; ++ni) {
        int row = wave_n + ni * 16 + col;
        int g = row * 8 + (kb ^ (row & 7));
        bf[ni] = *(const s16x8*)&smB[g * 8];
      }
      #pragma unroll
      for (int mi = 0; mi < 4; ++mi)
        #pragma unroll
        for (int ni = 0; ni < 4; ++ni)
          acc[mi][ni] = __builtin_amdgcn_mfma_f32_16x16x32_bf16(af[mi], bf[ni], acc[mi][ni], 0, 0, 0);
    }
  }

  // -------- epilogue: per-token top2 over this wave's 64 codes --------
  __syncthreads();                          // safe to reuse smA as scratch
  float* epv1 = (float*)smA;                // [4 waves][64 rows]
  float* epv2 = epv1 + 256;
  int*   epi1 = (int*)(epv2 + 256);

  #pragma unroll
  for (int mi = 0; mi < 4; ++mi) {
    #pragma unroll
    for (int r = 0; r < 4; ++r) {
      float v1 = -3.0e38f, v2 = -3.0e38f; int i1 = 0;
      #pragma unroll
      for (int ni = 0; ni < 4; ++ni) {
        float v = acc[mi][ni][r];
        int code = n0 + wave_n + ni * 16 + col;
        if (v > v1) { v2 = v1; v1 = v; i1 = code; }
        else if (v > v2) { v2 = v; }
      }
      #pragma unroll
      for (int off = 1; off < 16; off <<= 1) {   // reduce across the 16 cols of this quad
        float ov1 = __shfl_xor(v1, off);
        float ov2 = __shfl_xor(v2, off);
        int   oi1 = __shfl_xor(i1, off);
        if (ov1 > v1) { v2 = fmaxf(v1, ov2); v1 = ov1; i1 = oi1; }
        else          { v2 = fmaxf(v2, ov1); }
      }
      if (col == 0) {
        int rw = mi * 16 + quad * 4 + r;         // row within wave (0..63)
        epv1[wave * 64 + rw] = v1;
        epv2[wave * 64 + rw] = v2;
        epi1[wave * 64 + rw] = i1;
      }
    }
  }
  __syncthreads();
  {
    int token_local = tid & 127, half = tid >> 7;
    int w = (token_local >> 6) + half * 2;       // source wave
    int rloc = token_local & 63;
    int tile64 = blockIdx.x * 2 + half;          // 64-code tile id (0..127)
    size_t o = (size_t)tile64 * NTOK + (m0 + token_local);
    rv1[o] = epv1[w * 64 + rloc];
    rv2[o] = epv2[w * 64 + rloc];
    ri1[o] = epi1[w * 64 + rloc];
  }
}

// ---------------- K3: exact fp64 candidate rescore -> final idx ----------------
// one wave per token
__global__ __launch_bounds__(64) void k_select(const float* __restrict__ x,
                                               const float* __restrict__ wgt,
                                               const float* __restrict__ rv1,
                                               const float* __restrict__ rv2,
                                               const int* __restrict__ ri1,
                                               int* __restrict__ idxi,
                                               float* __restrict__ out_idx,
                                               float* __restrict__ counts) {
  const int t = blockIdx.x;
  const int lane = threadIdx.x;

  // global approx max over the 128 tile-top1s
  float g1 = rv1[(size_t)lane * NTOK + t];
  float g2 = rv1[(size_t)(lane + 64) * NTOK + t];
  float gm = fmaxf(g1, g2);
  #pragma unroll
  for (int off = 32; off > 0; off >>= 1) gm = fmaxf(gm, __shfl_xor(gm, off));
  const float thresh = gm - MARGIN;

  // preload this token's raw x row (8 elems/lane) as fp64
  const float* xr = x + (size_t)t * DIM + lane * 8;
  float4 x0 = *(const float4*)xr;
  float4 x1 = *(const float4*)(xr + 4);
  double xv[8] = {x0.x, x0.y, x0.z, x0.w, x1.x, x1.y, x1.z, x1.w};

  double bestv = -1e300; int besti = 1 << 30;
  auto evalc = [&](int c) {
    const float* wr = wgt + (size_t)c * DIM + lane * 8;
    float4 w0 = *(const float4*)wr;
    float4 w1 = *(const float4*)(wr + 4);
    double s  = (double)w0.x * xv[0] + (double)w0.y * xv[1] + (double)w0.z * xv[2] + (double)w0.w * xv[3]
              + (double)w1.x * xv[4] + (double)w1.y * xv[5] + (double)w1.z * xv[6] + (double)w1.w * xv[7];
    double nw = (double)w0.x * w0.x + (double)w0.y * w0.y + (double)w0.z * w0.z + (double)w0.w * w0.w
              + (double)w1.x * w1.x + (double)w1.y * w1.y + (double)w1.z * w1.z + (double)w1.w * w1.w;
    #pragma unroll
    for (int off = 1; off < 64; off <<= 1) { s += __shfl_xor(s, off); nw += __shfl_xor(nw, off); }
    double sim = s / sqrt(nw + 1e-12);      // x-norm omitted: constant per token
    if (sim > bestv || (sim == bestv && c < besti)) { bestv = sim; besti = c; }
  };

  for (int j = 0; j < 128; ++j) {
    float v1 = rv1[(size_t)j * NTOK + t];
    if (v1 >= thresh) evalc(ri1[(size_t)j * NTOK + t]);
    float v2 = rv2[(size_t)j * NTOK + t];
    if (v2 >= thresh) {                     // rare: second candidate inside same tile
      for (int c0 = 0; c0 < 64; ++c0) evalc(j * 64 + c0);
    }
  }
  if (lane == 0) {
    idxi[t] = besti;
    out_idx[t] = (float)besti;
    atomicAdd(&counts[besti], 1.0f);
  }
}

// ---------------- K4: quantized gather + loss partials + dw scatter ----------------
__global__ __launch_bounds__(256) void k_quant(const float* __restrict__ x,
                                               const float* __restrict__ wgt,
                                               const int* __restrict__ idxi,
                                               float* __restrict__ out0,
                                               float* __restrict__ loss_part,
                                               float* __restrict__ dw) {
  const int tid = threadIdx.x, lane = tid & 63, wave = tid >> 6;
  const size_t e = (size_t)blockIdx.x * 256 + tid;
  const int t = (int)(e >> 9), d = (int)(e & 511);
  const int id = idxi[t];
  const float q = wgt[(size_t)id * DIM + d];
  const float xv = x[e];
  out0[e] = q;
  float d2 = (q - xv) * (q - xv);
  #pragma unroll
  for (int off = 32; off > 0; off >>= 1) d2 += __shfl_xor(d2, off);
  __shared__ float ls[4];
  if (lane == 0) ls[wave] = d2;
  __syncthreads();
  if (tid == 0) loss_part[blockIdx.x] = ls[0] + ls[1] + ls[2] + ls[3];
  atomicAdd(&dw[(size_t)id * DIM + d], xv);
}

// ---------------- K5: pre-smoothing cluster sizes ----------------
__global__ __launch_bounds__(256) void k_cs(const float* __restrict__ cs,
                                            const float* __restrict__ counts,
                                            float* __restrict__ pre) {
  const int k = blockIdx.x * 256 + threadIdx.x;
  pre[k] = cs[k] * 0.99f + 0.01f * counts[k];
}

// ---------------- K6: scalar reductions (n, loss) ----------------
__global__ __launch_bounds__(256) void k_scalars(const float* __restrict__ pre,
                                                 const float* __restrict__ lp,
                                                 double* __restrict__ nacc,
                                                 float* __restrict__ out1) {
  __shared__ double red[256];
  const int tid = threadIdx.x;
  double s = 0.0;
  for (int i = tid; i < KCB; i += 256) s += (double)pre[i];
  red[tid] = s; __syncthreads();
  for (int st = 128; st > 0; st >>= 1) { if (tid < st) red[tid] += red[tid + st]; __syncthreads(); }
  if (tid == 0) *nacc = red[0];
  __syncthreads();
  double l = 0.0;
  for (int i = tid; i < 32768; i += 256) l += (double)lp[i];
  red[tid] = l; __syncthreads();
  for (int st = 128; st > 0; st >>= 1) { if (tid < st) red[tid] += red[tid + st]; __syncthreads(); }
  if (tid == 0) out1[0] = (float)(red[0] / (double)((size_t)NTOK * DIM));
}

// ---------------- K7: EMA finalize ----------------
__global__ __launch_bounds__(256) void k_final(const float* __restrict__ ema_w,
                                               const float* __restrict__ dw,
                                               const float* __restrict__ pre,
                                               const double* __restrict__ nacc,
                                               float* __restrict__ out3,
                                               float* __restrict__ out4,
                                               float* __restrict__ out5) {
  const size_t e = (size_t)blockIdx.x * 256 + threadIdx.x;
  const int k = (int)(e >> 9), d = (int)(e & 511);
  const double n = *nacc;
  const float csf = (float)(((double)pre[k] + 1e-5) / (n + (double)KCB * 1e-5) * n);
  const float nev = ema_w[e] * 0.99f + 0.01f * dw[e];
  out4[e] = nev;
  out5[e] = nev / csf;
  if (d == 0) out3[k] = csf;
}

// ---------------- launch ----------------
extern "C" void kernel_launch(void* const* d_in, const int* in_sizes, int n_in,
                              void* d_out, int out_size, void* d_ws, size_t ws_size,
                              hipStream_t stream) {
  const float* x    = (const float*)d_in[0];   // [8,2048,512]
  const float* wgt  = (const float*)d_in[1];   // [8192,512]
  const float* cs   = (const float*)d_in[2];   // [8192]
  const float* emaw = (const float*)d_in[3];   // [8192,512]

  char* ws = (char*)d_ws;
  unsigned short* xn  = (unsigned short*)(ws + WS_XN);
  unsigned short* wn  = (unsigned short*)(ws + WS_WN);
  float* rv1   = (float*)(ws + WS_RV1);
  float* rv2   = (float*)(ws + WS_RV2);
  int*   ri1   = (int*)(ws + WS_RI1);
  int*   idxi  = (int*)(ws + WS_IDX);
  float* lp    = (float*)(ws + WS_LP);
  float* pre   = (float*)(ws + WS_PRE);
  double* nacc = (double*)(ws + WS_N);
  float* dw    = (float*)(ws + WS_DW);
  float* cnt   = (float*)(ws + WS_CNT);

  float* out0 = (float*)d_out;            // quantized_st [8388608]
  float* out1 = out0 + 8388608;           // loss [1]
  float* out2 = out1 + 1;                 // idx  [16384]
  float* out3 = out2 + NTOK;              // new_cs [8192]
  float* out4 = out3 + KCB;               // new_ema_w [4194304]
  float* out5 = out4 + (size_t)KCB * DIM; // new_weight [4194304]

  // zero dw + counts (single contiguous region)
  hipMemsetAsync(ws + WS_DW, 0, WS_END - WS_DW, stream);

  k_normalize<<<NTOK + KCB, 256, 0, stream>>>(x, wgt, xn, wn);
  k_gemm_top2<<<dim3(64, 128), 256, 0, stream>>>(xn, wn, rv1, rv2, ri1);
  k_select<<<NTOK, 64, 0, stream>>>(x, wgt, rv1, rv2, ri1, idxi, out2, cnt);
  k_quant<<<32768, 256, 0, stream>>>(x, wgt, idxi, out0, lp, dw);
  k_cs<<<KCB / 256, 256, 0, stream>>>(cs, cnt, pre);
  k_scalars<<<1, 256, 0, stream>>>(pre, lp, nacc, out1);
  k_final<<<(KCB * DIM) / 256, 256, 0, stream>>>(emaw, dw, pre, nacc, out3, out4, out5);
}

// Round 2
// 677.580 us; speedup vs baseline: 1.0294x; 1.0294x over previous
//
#include <hip/hip_runtime.h>
#include <cstdint>
#include <cstddef>

// ---------------- problem constants ----------------
#define NTOK 16384          // 8*2048 tokens
#define DIM  512
#define KCB  8192           // codebook entries
#define MARGIN 6.0e-3f      // > worst-case bf16 screening error (2*2^-9*sum|xw| + slack)

typedef short s16x8 __attribute__((ext_vector_type(8)));   // 8 bf16 in 4 VGPRs
typedef float f32x4 __attribute__((ext_vector_type(4)));

// ---------------- workspace layout (bytes) ----------------
static const size_t WS_XN  = 0;                  // ushort[NTOK*DIM]  bf16 normalized x (16 MB)
static const size_t WS_WN  = 16777216;           // ushort[KCB*DIM]   bf16 normalized w (8 MB)
static const size_t WS_RV1 = 25165824;           // float[64*NTOK]    per-(tile128,token) top1 (4 MB)
static const size_t WS_RV2 = 29360128;           // float[64*NTOK]    top2 (4 MB)
static const size_t WS_RI1 = 33554432;           // int  [64*NTOK]    top1 code id (4 MB)
static const size_t WS_IDX = 37748736;           // int  [NTOK]
static const size_t WS_LP  = 37814272;           // float[32768]      loss partials
static const size_t WS_PRE = 37945344;           // float[KCB]        pre-smoothing cs
static const size_t WS_N   = 37978112;           // double            n = sum(new_cs)
static const size_t WS_CNT = 37978368;           // float[KCB]        counts (zeroed, 32 KB)
static const size_t WS_END = 38011136;

// ---------------- helpers ----------------
__device__ __forceinline__ void gl_lds16(const void* g, void* l) {
  // async 16B global->LDS; LDS dest is wave-uniform base + lane*16
  __builtin_amdgcn_global_load_lds(
      (__attribute__((address_space(1))) void*)(uintptr_t)g,
      (__attribute__((address_space(3))) void*)(uint32_t)(uintptr_t)l,
      16, 0, 0);
}

__device__ __forceinline__ unsigned short f2bf(float f) {
  unsigned int u = __float_as_uint(f);
  u = (u + 0x7fffu + ((u >> 16) & 1u)) >> 16;   // RNE
  return (unsigned short)u;
}

// ---------------- K1: l2-normalize x and w rows into bf16 ----------------
__global__ __launch_bounds__(256) void k_normalize(const float* __restrict__ x,
                                                   const float* __restrict__ w,
                                                   unsigned short* __restrict__ xn,
                                                   unsigned short* __restrict__ wn) {
  const int row = blockIdx.x;
  const int tid = threadIdx.x, lane = tid & 63, wave = tid >> 6;
  const float* src;
  unsigned short* dst;
  if (row < NTOK) { src = x + (size_t)row * DIM;          dst = xn + (size_t)row * DIM; }
  else            { src = w + (size_t)(row - NTOK) * DIM; dst = wn + (size_t)(row - NTOK) * DIM; }
  const int e = tid * 2;
  float2 v = *(const float2*)(src + e);
  float ss = v.x * v.x + v.y * v.y;
  #pragma unroll
  for (int off = 32; off > 0; off >>= 1) ss += __shfl_xor(ss, off);
  __shared__ float red[4];
  if (lane == 0) red[wave] = ss;
  __syncthreads();
  const float s = red[0] + red[1] + red[2] + red[3];
  const float inv = rsqrtf(s + 1e-12f);
  unsigned int lo = f2bf(v.x * inv), hi = f2bf(v.y * inv);
  *(unsigned int*)(dst + e) = lo | (hi << 16);
}

// ---------------- K2: bf16 MFMA GEMM (128x128 tile, BK=64) + top2 epilogue ----------------
// grid: (64 n-tiles, 128 m-tiles); block 256 = 4 waves in 2x2 arrangement
// records: top2 per (token, 128-code block-tile) -> 64 records/token
__global__ __launch_bounds__(256) void k_gemm_top2(const unsigned short* __restrict__ xn,
                                                   const unsigned short* __restrict__ wn,
                                                   float* __restrict__ rv1,
                                                   float* __restrict__ rv2,
                                                   int* __restrict__ ri1) {
  __shared__ __align__(16) unsigned short smA[128 * 64];
  __shared__ __align__(16) unsigned short smB[128 * 64];
  const int tid = threadIdx.x, wave = tid >> 6, lane = tid & 63;
  const int quad = lane >> 4, col = lane & 15;
  const int wave_m = (wave & 1) * 64, wave_n = (wave >> 1) * 64;
  const int n0 = blockIdx.x * 128, m0 = blockIdx.y * 128;

  // ---- hoisted staging pointers (advance by 64 elems = 128 B per kt) ----
  const unsigned short* pA[4];
  const unsigned short* pB[4];
  unsigned short* dA[4];
  unsigned short* dB[4];
  #pragma unroll
  for (int i = 0; i < 4; ++i) {
    int s = wave * 256 + i * 64 + lane;
    int row = s >> 3, cg = (s & 7) ^ (row & 7);
    pA[i] = xn + (size_t)(m0 + row) * DIM + cg * 8;
    pB[i] = wn + (size_t)(n0 + row) * DIM + cg * 8;
    dA[i] = &smA[(size_t)(wave * 256 + i * 64) * 8];
    dB[i] = &smB[(size_t)(wave * 256 + i * 64) * 8];
  }

  // ---- hoisted fragment LDS byte offsets (kt-invariant) ----
  int offA[4][2], offB[4][2];
  #pragma unroll
  for (int mi = 0; mi < 4; ++mi) {
    int rowA = wave_m + mi * 16 + col;
    int rowB = wave_n + mi * 16 + col;
    #pragma unroll
    for (int kbi = 0; kbi < 2; ++kbi) {
      int kb = kbi * 4 + quad;
      offA[mi][kbi] = (rowA * 8 + (kb ^ (rowA & 7))) * 16;
      offB[mi][kbi] = (rowB * 8 + (kb ^ (rowB & 7))) * 16;
    }
  }

  f32x4 acc[4][4] = {};
  const char* sA = (const char*)smA;
  const char* sB = (const char*)smB;

  #pragma unroll 1
  for (int kt = 0; kt < 8; ++kt) {
    __syncthreads();                       // everyone done reading previous tiles
    #pragma unroll
    for (int i = 0; i < 4; ++i) { gl_lds16(pA[i], dA[i]); pA[i] += 64; }
    #pragma unroll
    for (int i = 0; i < 4; ++i) { gl_lds16(pB[i], dB[i]); pB[i] += 64; }
    __syncthreads();                       // drains vmcnt before barrier
    #pragma unroll
    for (int kbi = 0; kbi < 2; ++kbi) {
      s16x8 af[4], bfr[4];
      #pragma unroll
      for (int mi = 0; mi < 4; ++mi) af[mi]  = *(const s16x8*)(sA + offA[mi][kbi]);
      #pragma unroll
      for (int ni = 0; ni < 4; ++ni) bfr[ni] = *(const s16x8*)(sB + offB[ni][kbi]);
      #pragma unroll
      for (int mi = 0; mi < 4; ++mi)
        #pragma unroll
        for (int ni = 0; ni < 4; ++ni)
          acc[mi][ni] = __builtin_amdgcn_mfma_f32_16x16x32_bf16(af[mi], bfr[ni], acc[mi][ni], 0, 0, 0);
    }
  }

  // -------- epilogue: per-token top2 over this wave's 64 codes --------
  __syncthreads();                          // safe to reuse smA as scratch
  float* epv1 = (float*)smA;                // [4 waves][64 rows]
  float* epv2 = epv1 + 256;
  int*   epi1 = (int*)(epv2 + 256);

  #pragma unroll
  for (int mi = 0; mi < 4; ++mi) {
    #pragma unroll
    for (int r = 0; r < 4; ++r) {
      float v1 = -3.0e38f, v2 = -3.0e38f; int i1 = 0;
      #pragma unroll
      for (int ni = 0; ni < 4; ++ni) {
        float v = acc[mi][ni][r];
        int code = n0 + wave_n + ni * 16 + col;
        if (v > v1) { v2 = v1; v1 = v; i1 = code; }
        else if (v > v2) { v2 = v; }
      }
      #pragma unroll
      for (int off = 1; off < 16; off <<= 1) {   // reduce across the 16 cols of this quad
        float ov1 = __shfl_xor(v1, off);
        float ov2 = __shfl_xor(v2, off);
        int   oi1 = __shfl_xor(i1, off);
        if (ov1 > v1) { v2 = fmaxf(v1, ov2); v1 = ov1; i1 = oi1; }
        else          { v2 = fmaxf(v2, ov1); }
      }
      if (col == 0) {
        int rw = mi * 16 + quad * 4 + r;         // row within wave (0..63)
        epv1[wave * 64 + rw] = v1;
        epv2[wave * 64 + rw] = v2;
        epi1[wave * 64 + rw] = i1;
      }
    }
  }
  __syncthreads();
  // merge wave pairs (same m rows, two 64-code halves) -> one record per 128 codes
  if (tid < 128) {
    int w0 = tid >> 6;                      // m-half: waves w0 and w0+2
    int rloc = tid & 63;
    float a1 = epv1[w0 * 64 + rloc], a2 = epv2[w0 * 64 + rloc];
    int   ai = epi1[w0 * 64 + rloc];
    float b1 = epv1[(w0 + 2) * 64 + rloc], b2 = epv2[(w0 + 2) * 64 + rloc];
    int   bi = epi1[(w0 + 2) * 64 + rloc];
    float v1, v2; int i1;
    if (a1 >= b1) { v1 = a1; i1 = ai; v2 = fmaxf(a2, b1); }
    else          { v1 = b1; i1 = bi; v2 = fmaxf(b2, a1); }
    size_t o = (size_t)blockIdx.x * NTOK + (m0 + tid);
    rv1[o] = v1;
    rv2[o] = v2;
    ri1[o] = i1;
  }
}

// ---------------- K3: exact fp64 candidate rescore -> final idx ----------------
// one wave per token; 64 records/token, one per lane
__global__ __launch_bounds__(64) void k_select(const float* __restrict__ x,
                                               const float* __restrict__ wgt,
                                               const float* __restrict__ rv1,
                                               const float* __restrict__ rv2,
                                               const int* __restrict__ ri1,
                                               int* __restrict__ idxi,
                                               float* __restrict__ out_idx,
                                               float* __restrict__ counts) {
  const int t = blockIdx.x;
  const int lane = threadIdx.x;

  const float v1 = rv1[(size_t)lane * NTOK + t];
  const float v2 = rv2[(size_t)lane * NTOK + t];
  const int   i1 = ri1[(size_t)lane * NTOK + t];

  float gm = v1;
  #pragma unroll
  for (int off = 32; off > 0; off >>= 1) gm = fmaxf(gm, __shfl_xor(gm, off));
  const float thresh = gm - MARGIN;

  unsigned long long m1 = __ballot(v1 >= thresh);
  unsigned long long m2 = __ballot(v2 >= thresh);

  // preload this token's raw x row (8 elems/lane) as fp64
  const float* xr = x + (size_t)t * DIM + lane * 8;
  float4 x0 = *(const float4*)xr;
  float4 x1 = *(const float4*)(xr + 4);
  double xv[8] = {x0.x, x0.y, x0.z, x0.w, x1.x, x1.y, x1.z, x1.w};

  double bestv = -1e300; int besti = 1 << 30;
  auto evalc = [&](int c) {
    const float* wr = wgt + (size_t)c * DIM + lane * 8;
    float4 w0 = *(const float4*)wr;
    float4 w1 = *(const float4*)(wr + 4);
    double s  = (double)w0.x * xv[0] + (double)w0.y * xv[1] + (double)w0.z * xv[2] + (double)w0.w * xv[3]
              + (double)w1.x * xv[4] + (double)w1.y * xv[5] + (double)w1.z * xv[6] + (double)w1.w * xv[7];
    double nw = (double)w0.x * w0.x + (double)w0.y * w0.y + (double)w0.z * w0.z + (double)w0.w * w0.w
              + (double)w1.x * w1.x + (double)w1.y * w1.y + (double)w1.z * w1.z + (double)w1.w * w1.w;
    #pragma unroll
    for (int off = 1; off < 64; off <<= 1) { s += __shfl_xor(s, off); nw += __shfl_xor(nw, off); }
    double sim = s / sqrt(nw + 1e-12);      // x-norm omitted: constant per token
    if (sim > bestv || (sim == bestv && c < besti)) { bestv = sim; besti = c; }
  };

  while (m1) {
    int b = __builtin_ctzll(m1); m1 &= m1 - 1;
    int c = __shfl(i1, b);
    evalc(c);
  }
  while (m2) {                              // rare: second candidate inside same 128-tile
    int b = __builtin_ctzll(m2); m2 &= m2 - 1;
    for (int c0 = 0; c0 < 128; ++c0) evalc(b * 128 + c0);
  }

  if (lane == 0) {
    idxi[t] = besti;
    out_idx[t] = (float)besti;
    atomicAdd(&counts[besti], 1.0f);
  }
}

// ---------------- K4a: pre-init new_ema_w = 0.99*ema_w (atomics land on top) ----------------
__global__ __launch_bounds__(256) void k_init_ema(const float* __restrict__ ema_w,
                                                  float* __restrict__ out4) {
  const size_t e = (size_t)blockIdx.x * 256 + threadIdx.x;
  out4[e] = ema_w[e] * 0.99f;
}

// ---------------- K4: quantized gather + loss partials + dw scatter into out4 ----------------
__global__ __launch_bounds__(256) void k_quant(const float* __restrict__ x,
                                               const float* __restrict__ wgt,
                                               const int* __restrict__ idxi,
                                               float* __restrict__ out0,
                                               float* __restrict__ loss_part,
                                               float* __restrict__ out4) {
  const int tid = threadIdx.x, lane = tid & 63, wave = tid >> 6;
  const size_t e = (size_t)blockIdx.x * 256 + tid;
  const int t = (int)(e >> 9), d = (int)(e & 511);
  const int id = idxi[t];
  const float q = wgt[(size_t)id * DIM + d];
  const float xv = x[e];
  out0[e] = q;
  float d2 = (q - xv) * (q - xv);
  #pragma unroll
  for (int off = 32; off > 0; off >>= 1) d2 += __shfl_xor(d2, off);
  __shared__ float ls[4];
  if (lane == 0) ls[wave] = d2;
  __syncthreads();
  if (tid == 0) loss_part[blockIdx.x] = ls[0] + ls[1] + ls[2] + ls[3];
  atomicAdd(&out4[(size_t)id * DIM + d], 0.01f * xv);
}

// ---------------- K6: scalar reductions (pre-cs, n, loss) ----------------
__global__ __launch_bounds__(256) void k_scalars(const float* __restrict__ cs,
                                                 const float* __restrict__ counts,
                                                 float* __restrict__ pre,
                                                 const float* __restrict__ lp,
                                                 double* __restrict__ nacc,
                                                 float* __restrict__ out1) {
  __shared__ double red[256];
  const int tid = threadIdx.x;
  double s = 0.0;
  for (int i = tid; i < KCB; i += 256) {
    float p = cs[i] * 0.99f + 0.01f * counts[i];
    pre[i] = p;
    s += (double)p;
  }
  red[tid] = s; __syncthreads();
  for (int st = 128; st > 0; st >>= 1) { if (tid < st) red[tid] += red[tid + st]; __syncthreads(); }
  if (tid == 0) *nacc = red[0];
  __syncthreads();
  double l = 0.0;
  for (int i = tid; i < 32768; i += 256) l += (double)lp[i];
  red[tid] = l; __syncthreads();
  for (int st = 128; st > 0; st >>= 1) { if (tid < st) red[tid] += red[tid + st]; __syncthreads(); }
  if (tid == 0) out1[0] = (float)(red[0] / (double)((size_t)NTOK * DIM));
}

// ---------------- K7: EMA finalize ----------------
__global__ __launch_bounds__(256) void k_final(const float* __restrict__ out4,
                                               const float* __restrict__ pre,
                                               const double* __restrict__ nacc,
                                               float* __restrict__ out3,
                                               float* __restrict__ out5) {
  const size_t e = (size_t)blockIdx.x * 256 + threadIdx.x;
  const int k = (int)(e >> 9), d = (int)(e & 511);
  const double n = *nacc;
  const float csf = (float)(((double)pre[k] + 1e-5) / (n + (double)KCB * 1e-5) * n);
  out5[e] = out4[e] / csf;
  if (d == 0) out3[k] = csf;
}

// ---------------- launch ----------------
extern "C" void kernel_launch(void* const* d_in, const int* in_sizes, int n_in,
                              void* d_out, int out_size, void* d_ws, size_t ws_size,
                              hipStream_t stream) {
  const float* x    = (const float*)d_in[0];   // [8,2048,512]
  const float* wgt  = (const float*)d_in[1];   // [8192,512]
  const float* cs   = (const float*)d_in[2];   // [8192]
  const float* emaw = (const float*)d_in[3];   // [8192,512]

  char* ws = (char*)d_ws;
  unsigned short* xn  = (unsigned short*)(ws + WS_XN);
  unsigned short* wn  = (unsigned short*)(ws + WS_WN);
  float* rv1   = (float*)(ws + WS_RV1);
  float* rv2   = (float*)(ws + WS_RV2);
  int*   ri1   = (int*)(ws + WS_RI1);
  int*   idxi  = (int*)(ws + WS_IDX);
  float* lp    = (float*)(ws + WS_LP);
  float* pre   = (float*)(ws + WS_PRE);
  double* nacc = (double*)(ws + WS_N);
  float* cnt   = (float*)(ws + WS_CNT);

  float* out0 = (float*)d_out;            // quantized_st [8388608]
  float* out1 = out0 + 8388608;           // loss [1]
  float* out2 = out1 + 1;                 // idx  [16384]
  float* out3 = out2 + NTOK;              // new_cs [8192]
  float* out4 = out3 + KCB;               // new_ema_w [4194304]
  float* out5 = out4 + (size_t)KCB * DIM; // new_weight [4194304]

  hipMemsetAsync(cnt, 0, KCB * sizeof(float), stream);

  k_normalize<<<NTOK + KCB, 256, 0, stream>>>(x, wgt, xn, wn);
  k_init_ema<<<(KCB * DIM) / 256, 256, 0, stream>>>(emaw, out4);
  k_gemm_top2<<<dim3(64, 128), 256, 0, stream>>>(xn, wn, rv1, rv2, ri1);
  k_select<<<NTOK, 64, 0, stream>>>(x, wgt, rv1, rv2, ri1, idxi, out2, cnt);
  k_quant<<<32768, 256, 0, stream>>>(x, wgt, idxi, out0, lp, out4);
  k_scalars<<<1, 256, 0, stream>>>(cs, cnt, pre, lp, nacc, out1);
  k_final<<<(KCB * DIM) / 256, 256, 0, stream>>>(out4, pre, nacc, out3, out5);
}

// Round 4
// 528.129 us; speedup vs baseline: 1.3207x; 1.2830x over previous
//
#include <hip/hip_runtime.h>
#include <cstdint>
#include <cstddef>

// ---------------- problem constants ----------------
#define NTOK 16384          // 8*2048 tokens
#define DIM  512
#define KCB  8192           // codebook entries
#define MARGIN 6.0e-3f      // > worst-case bf16 screening error
#define LISTCAP 512         // max tokens per code (avg ~2, Poisson-ish)

typedef short s16x8 __attribute__((ext_vector_type(8)));   // 8 bf16 in 4 VGPRs
typedef float f32x4 __attribute__((ext_vector_type(4)));

// ---------------- workspace layout (bytes) — gap-free, no overlaps ----------------
static const size_t WS_XN   = 0;           // ushort[NTOK*DIM]   bf16 normalized x  -> 16777216
static const size_t WS_WN   = 16777216;    // ushort[KCB*DIM]    bf16 normalized w  -> 25165824
static const size_t WS_RV1  = 25165824;    // float[64*NTOK]     top1               -> 29360128
static const size_t WS_RV2  = 29360128;    // float[64*NTOK]     top2               -> 33554432
static const size_t WS_RI1  = 33554432;    // int  [64*NTOK]     top1 code id       -> 37748736
static const size_t WS_LP   = 37748736;    // float[NTOK]        loss partials      -> 37814272
static const size_t WS_PRE  = 37814272;    // float[KCB]         pre-smoothing cs   -> 37847040
static const size_t WS_N    = 37847040;    // double             n (256B pad)       -> 37847296
static const size_t WS_CNT  = 37847296;    // int[KCB]           counts (zeroed)    -> 37880064
static const size_t WS_LIST = 37880064;    // int[KCB*LISTCAP]   token lists        -> 54657280

// ---------------- helpers ----------------
__device__ __forceinline__ void gl_lds16(const void* g, void* l) {
  // async 16B global->LDS; LDS dest is wave-uniform base + lane*16
  __builtin_amdgcn_global_load_lds(
      (__attribute__((address_space(1))) void*)(uintptr_t)g,
      (__attribute__((address_space(3))) void*)(uint32_t)(uintptr_t)l,
      16, 0, 0);
}

__device__ __forceinline__ unsigned short f2bf(float f) {
  unsigned int u = __float_as_uint(f);
  u = (u + 0x7fffu + ((u >> 16) & 1u)) >> 16;   // RNE
  return (unsigned short)u;
}

// ---------------- K1: l2-normalize x and w rows into bf16 ----------------
__global__ __launch_bounds__(256) void k_normalize(const float* __restrict__ x,
                                                   const float* __restrict__ w,
                                                   unsigned short* __restrict__ xn,
                                                   unsigned short* __restrict__ wn) {
  const int row = blockIdx.x;
  const int tid = threadIdx.x, lane = tid & 63, wave = tid >> 6;
  const float* src;
  unsigned short* dst;
  if (row < NTOK) { src = x + (size_t)row * DIM;          dst = xn + (size_t)row * DIM; }
  else            { src = w + (size_t)(row - NTOK) * DIM; dst = wn + (size_t)(row - NTOK) * DIM; }
  const int e = tid * 2;
  float2 v = *(const float2*)(src + e);
  float ss = v.x * v.x + v.y * v.y;
  #pragma unroll
  for (int off = 32; off > 0; off >>= 1) ss += __shfl_xor(ss, off);
  __shared__ float red[4];
  if (lane == 0) red[wave] = ss;
  __syncthreads();
  const float s = red[0] + red[1] + red[2] + red[3];
  const float inv = rsqrtf(s + 1e-12f);
  unsigned int lo = f2bf(v.x * inv), hi = f2bf(v.y * inv);
  *(unsigned int*)(dst + e) = lo | (hi << 16);
}

// ---------------- K2: bf16 MFMA GEMM, block 128m x 256n, wave 64m x 128n ----------------
// grid (32 n-tiles, 128 m-tiles); 4 waves: wave_m=(w&1)*64, wave_n=(w>>1)*128
// each wave emits its own per-(token,128-tile) top2 record -> no LDS epilogue
__global__ __launch_bounds__(256, 2) void k_gemm_top2(const unsigned short* __restrict__ xn,
                                                      const unsigned short* __restrict__ wn,
                                                      float* __restrict__ rv1,
                                                      float* __restrict__ rv2,
                                                      int* __restrict__ ri1) {
  __shared__ __align__(16) unsigned short smA[128 * 64];   // 16 KB
  __shared__ __align__(16) unsigned short smB[256 * 64];   // 32 KB
  const int tid = threadIdx.x, wave = tid >> 6, lane = tid & 63;
  const int quad = lane >> 4, col = lane & 15;
  const int wave_m = (wave & 1) * 64, wave_n = (wave >> 1) * 128;
  const int n0 = blockIdx.x * 256, m0 = blockIdx.y * 128;

  // ---- staging pointers (advance 64 elems per kt) ----
  const unsigned short* pA[4];
  const unsigned short* pB[8];
  unsigned short* dA[4];
  unsigned short* dB[8];
  #pragma unroll
  for (int i = 0; i < 4; ++i) {
    int s = wave * 256 + i * 64 + lane;
    int row = s >> 3, cg = (s & 7) ^ (row & 7);
    pA[i] = xn + (size_t)(m0 + row) * DIM + cg * 8;
    dA[i] = &smA[(size_t)(wave * 256 + i * 64) * 8];
  }
  #pragma unroll
  for (int i = 0; i < 8; ++i) {
    int s = wave * 512 + i * 64 + lane;
    int row = s >> 3, cg = (s & 7) ^ (row & 7);
    pB[i] = wn + (size_t)(n0 + row) * DIM + cg * 8;
    dB[i] = &smB[(size_t)(wave * 512 + i * 64) * 8];
  }

  // ---- fragment LDS byte offsets (kt-invariant) ----
  int offA[4][2], offB[8][2];
  #pragma unroll
  for (int kbi = 0; kbi < 2; ++kbi) {
    int kb = kbi * 4 + quad;
    #pragma unroll
    for (int mi = 0; mi < 4; ++mi) {
      int row = wave_m + mi * 16 + col;
      offA[mi][kbi] = (row * 8 + (kb ^ (row & 7))) * 16;
    }
    #pragma unroll
    for (int ni = 0; ni < 8; ++ni) {
      int row = wave_n + ni * 16 + col;
      offB[ni][kbi] = (row * 8 + (kb ^ (row & 7))) * 16;
    }
  }

  f32x4 acc[4][8] = {};
  const char* sA = (const char*)smA;
  const char* sB = (const char*)smB;

  #pragma unroll 1
  for (int kt = 0; kt < 8; ++kt) {
    __syncthreads();
    #pragma unroll
    for (int i = 0; i < 4; ++i) { gl_lds16(pA[i], dA[i]); pA[i] += 64; }
    #pragma unroll
    for (int i = 0; i < 8; ++i) { gl_lds16(pB[i], dB[i]); pB[i] += 64; }
    __syncthreads();
    #pragma unroll
    for (int kbi = 0; kbi < 2; ++kbi) {
      s16x8 af[4], bfr[8];
      #pragma unroll
      for (int mi = 0; mi < 4; ++mi) af[mi]  = *(const s16x8*)(sA + offA[mi][kbi]);
      #pragma unroll
      for (int ni = 0; ni < 8; ++ni) bfr[ni] = *(const s16x8*)(sB + offB[ni][kbi]);
      #pragma unroll
      for (int mi = 0; mi < 4; ++mi)
        #pragma unroll
        for (int ni = 0; ni < 8; ++ni)
          acc[mi][ni] = __builtin_amdgcn_mfma_f32_16x16x32_bf16(af[mi], bfr[ni], acc[mi][ni], 0, 0, 0);
    }
  }

  // -------- epilogue: per-row top2 over this wave's 128 codes, in-register --------
  const int tile = blockIdx.x * 2 + (wave >> 1);
  float resv1 = 0.f, resv2 = 0.f; int resi1 = 0;
  #pragma unroll
  for (int mi = 0; mi < 4; ++mi) {
    #pragma unroll
    for (int r = 0; r < 4; ++r) {
      const int p = mi * 4 + r;
      float v1 = -3.0e38f, v2 = -3.0e38f; int i1 = 0;
      #pragma unroll
      for (int ni = 0; ni < 8; ++ni) {
        float v = acc[mi][ni][r];
        int code = n0 + wave_n + ni * 16 + col;
        if (v > v1) { v2 = v1; v1 = v; i1 = code; }
        else if (v > v2) { v2 = v; }
      }
      #pragma unroll
      for (int off = 1; off < 16; off <<= 1) {   // butterfly over the 16 cols of this quad
        float ov1 = __shfl_xor(v1, off);
        float ov2 = __shfl_xor(v2, off);
        int   oi1 = __shfl_xor(i1, off);
        if (ov1 > v1) { v2 = fmaxf(v1, ov2); v1 = ov1; i1 = oi1; }
        else          { v2 = fmaxf(v2, ov1); }
      }
      if (col == p) { resv1 = v1; resv2 = v2; resi1 = i1; }  // lane-compact
    }
  }
  const int row = wave_m + (col >> 2) * 16 + quad * 4 + (col & 3);  // bijective over 64
  const size_t o = (size_t)tile * NTOK + (m0 + row);
  rv1[o] = resv1;
  rv2[o] = resv2;
  ri1[o] = resi1;
}

// ---------------- K3: exact fp64 rescore -> idx, fused quantized gather + loss + list ----------------
// one wave per token; 64 records/token, one per lane
__global__ __launch_bounds__(64) void k_select(const float* __restrict__ x,
                                               const float* __restrict__ wgt,
                                               const float* __restrict__ rv1,
                                               const float* __restrict__ rv2,
                                               const int* __restrict__ ri1,
                                               float* __restrict__ out0,
                                               float* __restrict__ out_idx,
                                               float* __restrict__ lp,
                                               int* __restrict__ cnt,
                                               int* __restrict__ list) {
  const int t = blockIdx.x;
  const int lane = threadIdx.x;

  const float v1 = rv1[(size_t)lane * NTOK + t];
  const float v2 = rv2[(size_t)lane * NTOK + t];
  const int   i1 = ri1[(size_t)lane * NTOK + t];

  float gm = v1;
  #pragma unroll
  for (int off = 32; off > 0; off >>= 1) gm = fmaxf(gm, __shfl_xor(gm, off));
  const float thresh = gm - MARGIN;

  unsigned long long m1 = __ballot(v1 >= thresh);
  unsigned long long m2 = __ballot(v2 >= thresh);

  const float* xr = x + (size_t)t * DIM + lane * 8;
  float4 x0 = *(const float4*)xr;
  float4 x1 = *(const float4*)(xr + 4);
  double xv[8] = {x0.x, x0.y, x0.z, x0.w, x1.x, x1.y, x1.z, x1.w};

  double bestv = -1e300; int besti = 1 << 30;
  auto evalc = [&](int c) {
    const float* wr = wgt + (size_t)c * DIM + lane * 8;
    float4 w0 = *(const float4*)wr;
    float4 w1 = *(const float4*)(wr + 4);
    double s  = (double)w0.x * xv[0] + (double)w0.y * xv[1] + (double)w0.z * xv[2] + (double)w0.w * xv[3]
              + (double)w1.x * xv[4] + (double)w1.y * xv[5] + (double)w1.z * xv[6] + (double)w1.w * xv[7];
    double nw = (double)w0.x * w0.x + (double)w0.y * w0.y + (double)w0.z * w0.z + (double)w0.w * w0.w
              + (double)w1.x * w1.x + (double)w1.y * w1.y + (double)w1.z * w1.z + (double)w1.w * w1.w;
    #pragma unroll
    for (int off = 1; off < 64; off <<= 1) { s += __shfl_xor(s, off); nw += __shfl_xor(nw, off); }
    double sim = s / sqrt(nw + 1e-12);      // x-norm omitted: constant per token
    if (sim > bestv || (sim == bestv && c < besti)) { bestv = sim; besti = c; }
  };

  while (m1) {
    int b = __builtin_ctzll(m1); m1 &= m1 - 1;
    evalc(__shfl(i1, b));
  }
  while (m2) {                              // rare: second candidate inside same 128-tile
    int b = __builtin_ctzll(m2); m2 &= m2 - 1;
    for (int c0 = 0; c0 < 128; ++c0) evalc(b * 128 + c0);
  }
  if ((unsigned)besti >= KCB) besti = 0;    // hardening: impossible per analysis, fault-proof anyway

  // fused: quantized gather + per-token loss partial
  const float* wr = wgt + (size_t)besti * DIM + lane * 8;
  float4 w0 = *(const float4*)wr;
  float4 w1 = *(const float4*)(wr + 4);
  float* o0 = out0 + (size_t)t * DIM + lane * 8;
  *(float4*)o0 = w0;
  *(float4*)(o0 + 4) = w1;
  double d2 = 0.0;
  double qv[8] = {w0.x, w0.y, w0.z, w0.w, w1.x, w1.y, w1.z, w1.w};
  #pragma unroll
  for (int j = 0; j < 8; ++j) { double d = qv[j] - xv[j]; d2 += d * d; }
  #pragma unroll
  for (int off = 1; off < 64; off <<= 1) d2 += __shfl_xor(d2, off);

  if (lane == 0) {
    lp[t] = (float)d2;
    out_idx[t] = (float)besti;
    int slot = atomicAdd(&cnt[besti], 1);
    if (slot < LISTCAP) list[besti * LISTCAP + slot] = t;
  }
}

// ---------------- K4: scalar reductions (pre-cs, n, loss) ----------------
__global__ __launch_bounds__(256) void k_scalars(const float* __restrict__ cs,
                                                 const int* __restrict__ cnt,
                                                 float* __restrict__ pre,
                                                 const float* __restrict__ lp,
                                                 double* __restrict__ nacc,
                                                 float* __restrict__ out1) {
  __shared__ double red[256];
  const int tid = threadIdx.x;
  double s = 0.0;
  for (int i = tid; i < KCB; i += 256) {
    float p = cs[i] * 0.99f + 0.01f * (float)cnt[i];
    pre[i] = p;
    s += (double)p;
  }
  red[tid] = s; __syncthreads();
  for (int st = 128; st > 0; st >>= 1) { if (tid < st) red[tid] += red[tid + st]; __syncthreads(); }
  if (tid == 0) *nacc = red[0];
  __syncthreads();
  double l = 0.0;
  for (int i = tid; i < NTOK; i += 256) l += (double)lp[i];
  red[tid] = l; __syncthreads();
  for (int st = 128; st > 0; st >>= 1) { if (tid < st) red[tid] += red[tid + st]; __syncthreads(); }
  if (tid == 0) out1[0] = (float)(red[0] / (double)((size_t)NTOK * DIM));
}

// ---------------- K5: per-code gather-sum + EMA finalize (one block per code) ----------------
__global__ __launch_bounds__(256) void k_dw(const float* __restrict__ x,
                                            const float* __restrict__ ema_w,
                                            const int* __restrict__ cnt,
                                            const int* __restrict__ list,
                                            const float* __restrict__ pre,
                                            const double* __restrict__ nacc,
                                            float* __restrict__ out3,
                                            float* __restrict__ out4,
                                            float* __restrict__ out5) {
  const int c = blockIdx.x, tid = threadIdx.x;
  int m = cnt[c]; if (m > LISTCAP) m = LISTCAP;
  const double n = *nacc;
  const float csf = (float)(((double)pre[c] + 1e-5) / (n + (double)KCB * 1e-5) * n);
  const int d0 = tid * 2;
  double s0 = 0.0, s1 = 0.0;
  for (int j = 0; j < m; ++j) {
    int t = list[c * LISTCAP + j] & (NTOK - 1);   // hardening: NTOK is pow2
    float2 v = *(const float2*)(x + (size_t)t * DIM + d0);
    s0 += (double)v.x; s1 += (double)v.y;
  }
  const size_t e = (size_t)c * DIM + d0;
  float n0 = ema_w[e]     * 0.99f + 0.01f * (float)s0;
  float n1 = ema_w[e + 1] * 0.99f + 0.01f * (float)s1;
  out4[e] = n0;       out4[e + 1] = n1;
  out5[e] = n0 / csf; out5[e + 1] = n1 / csf;
  if (tid == 0) out3[c] = csf;
}

// ---------------- launch ----------------
extern "C" void kernel_launch(void* const* d_in, const int* in_sizes, int n_in,
                              void* d_out, int out_size, void* d_ws, size_t ws_size,
                              hipStream_t stream) {
  const float* x    = (const float*)d_in[0];   // [8,2048,512]
  const float* wgt  = (const float*)d_in[1];   // [8192,512]
  const float* cs   = (const float*)d_in[2];   // [8192]
  const float* emaw = (const float*)d_in[3];   // [8192,512]

  char* ws = (char*)d_ws;
  unsigned short* xn  = (unsigned short*)(ws + WS_XN);
  unsigned short* wn  = (unsigned short*)(ws + WS_WN);
  float* rv1   = (float*)(ws + WS_RV1);
  float* rv2   = (float*)(ws + WS_RV2);
  int*   ri1   = (int*)(ws + WS_RI1);
  float* lp    = (float*)(ws + WS_LP);
  float* pre   = (float*)(ws + WS_PRE);
  double* nacc = (double*)(ws + WS_N);
  int*   cnt   = (int*)(ws + WS_CNT);
  int*   list  = (int*)(ws + WS_LIST);

  float* out0 = (float*)d_out;            // quantized_st [8388608]
  float* out1 = out0 + 8388608;           // loss [1]
  float* out2 = out1 + 1;                 // idx  [16384]
  float* out3 = out2 + NTOK;              // new_cs [8192]
  float* out4 = out3 + KCB;               // new_ema_w [4194304]
  float* out5 = out4 + (size_t)KCB * DIM; // new_weight [4194304]

  hipMemsetAsync(cnt, 0, KCB * sizeof(int), stream);

  k_normalize<<<NTOK + KCB, 256, 0, stream>>>(x, wgt, xn, wn);
  k_gemm_top2<<<dim3(32, 128), 256, 0, stream>>>(xn, wn, rv1, rv2, ri1);
  k_select<<<NTOK, 64, 0, stream>>>(x, wgt, rv1, rv2, ri1, out0, out2, lp, cnt, list);
  k_scalars<<<1, 256, 0, stream>>>(cs, cnt, pre, lp, nacc, out1);
  k_dw<<<KCB, 256, 0, stream>>>(x, emaw, cnt, list, pre, nacc, out3, out4, out5);
}

// Round 5
// 512.807 us; speedup vs baseline: 1.3601x; 1.0299x over previous
//
#include <hip/hip_runtime.h>
#include <cstdint>
#include <cstddef>

// ---------------- problem constants ----------------
#define NTOK 16384          // 8*2048 tokens
#define DIM  512
#define KCB  8192           // codebook entries
#define MARGIN 6.0e-3f      // > worst-case bf16 screening error
#define LISTCAP 512         // max tokens per code (avg ~2, Poisson-ish)

typedef short s16x8 __attribute__((ext_vector_type(8)));   // 8 bf16 in 4 VGPRs
typedef float f32x4 __attribute__((ext_vector_type(4)));

// ---------------- workspace layout (bytes) — gap-free, no overlaps ----------------
static const size_t WS_XN   = 0;           // ushort[NTOK*DIM]   bf16 normalized x  -> 16777216
static const size_t WS_WN   = 16777216;    // ushort[KCB*DIM]    bf16 normalized w  -> 25165824
static const size_t WS_RV1  = 25165824;    // float[NTOK*64]     top1 (token-major) -> 29360128
static const size_t WS_RV2  = 29360128;    // float[NTOK*64]     top2               -> 33554432
static const size_t WS_RI1  = 33554432;    // int  [NTOK*64]     top1 code id       -> 37748736
static const size_t WS_LP   = 37748736;    // float[NTOK]        loss partials      -> 37814272
static const size_t WS_PRE  = 37814272;    // float[KCB]         pre-smoothing cs   -> 37847040
static const size_t WS_N    = 37847040;    // double             n (256B pad)       -> 37847296
static const size_t WS_CNT  = 37847296;    // int[KCB]           counts (zeroed)    -> 37880064
static const size_t WS_LIST = 37880064;    // int[KCB*LISTCAP]   token lists        -> 54657280

// ---------------- helpers ----------------
__device__ __forceinline__ void gl_lds16(const void* g, void* l) {
  // async 16B global->LDS; LDS dest is wave-uniform base + lane*16
  __builtin_amdgcn_global_load_lds(
      (__attribute__((address_space(1))) void*)(uintptr_t)g,
      (__attribute__((address_space(3))) void*)(uint32_t)(uintptr_t)l,
      16, 0, 0);
}

__device__ __forceinline__ unsigned short f2bf(float f) {
  unsigned int u = __float_as_uint(f);
  u = (u + 0x7fffu + ((u >> 16) & 1u)) >> 16;   // RNE
  return (unsigned short)u;
}

// ---------------- K1: l2-normalize x and w rows into bf16 ----------------
__global__ __launch_bounds__(256) void k_normalize(const float* __restrict__ x,
                                                   const float* __restrict__ w,
                                                   unsigned short* __restrict__ xn,
                                                   unsigned short* __restrict__ wn) {
  const int row = blockIdx.x;
  const int tid = threadIdx.x, lane = tid & 63, wave = tid >> 6;
  const float* src;
  unsigned short* dst;
  if (row < NTOK) { src = x + (size_t)row * DIM;          dst = xn + (size_t)row * DIM; }
  else            { src = w + (size_t)(row - NTOK) * DIM; dst = wn + (size_t)(row - NTOK) * DIM; }
  const int e = tid * 2;
  float2 v = *(const float2*)(src + e);
  float ss = v.x * v.x + v.y * v.y;
  #pragma unroll
  for (int off = 32; off > 0; off >>= 1) ss += __shfl_xor(ss, off);
  __shared__ float red[4];
  if (lane == 0) red[wave] = ss;
  __syncthreads();
  const float s = red[0] + red[1] + red[2] + red[3];
  const float inv = rsqrtf(s + 1e-12f);
  unsigned int lo = f2bf(v.x * inv), hi = f2bf(v.y * inv);
  *(unsigned int*)(dst + e) = lo | (hi << 16);
}

// ---------------- K2: bf16 MFMA GEMM, block 128m x 256n, wave 64m x 128n ----------------
// grid (32 n-tiles, 128 m-tiles); 4 waves: wave_m=(w&1)*64, wave_n=(w>>1)*128
// records stored TOKEN-MAJOR: rv[t*64 + tile] so k_select reads are coalesced
__global__ __launch_bounds__(256, 2) void k_gemm_top2(const unsigned short* __restrict__ xn,
                                                      const unsigned short* __restrict__ wn,
                                                      float* __restrict__ rv1,
                                                      float* __restrict__ rv2,
                                                      int* __restrict__ ri1) {
  __shared__ __align__(16) unsigned short smA[128 * 64];   // 16 KB
  __shared__ __align__(16) unsigned short smB[256 * 64];   // 32 KB
  const int tid = threadIdx.x, wave = tid >> 6, lane = tid & 63;
  const int quad = lane >> 4, col = lane & 15;
  const int wave_m = (wave & 1) * 64, wave_n = (wave >> 1) * 128;
  const int n0 = blockIdx.x * 256, m0 = blockIdx.y * 128;

  // ---- staging pointers (advance 64 elems per kt) ----
  const unsigned short* pA[4];
  const unsigned short* pB[8];
  unsigned short* dA[4];
  unsigned short* dB[8];
  #pragma unroll
  for (int i = 0; i < 4; ++i) {
    int s = wave * 256 + i * 64 + lane;
    int row = s >> 3, cg = (s & 7) ^ (row & 7);
    pA[i] = xn + (size_t)(m0 + row) * DIM + cg * 8;
    dA[i] = &smA[(size_t)(wave * 256 + i * 64) * 8];
  }
  #pragma unroll
  for (int i = 0; i < 8; ++i) {
    int s = wave * 512 + i * 64 + lane;
    int row = s >> 3, cg = (s & 7) ^ (row & 7);
    pB[i] = wn + (size_t)(n0 + row) * DIM + cg * 8;
    dB[i] = &smB[(size_t)(wave * 512 + i * 64) * 8];
  }

  // ---- fragment LDS byte offsets (kt-invariant) ----
  int offA[4][2], offB[8][2];
  #pragma unroll
  for (int kbi = 0; kbi < 2; ++kbi) {
    int kb = kbi * 4 + quad;
    #pragma unroll
    for (int mi = 0; mi < 4; ++mi) {
      int row = wave_m + mi * 16 + col;
      offA[mi][kbi] = (row * 8 + (kb ^ (row & 7))) * 16;
    }
    #pragma unroll
    for (int ni = 0; ni < 8; ++ni) {
      int row = wave_n + ni * 16 + col;
      offB[ni][kbi] = (row * 8 + (kb ^ (row & 7))) * 16;
    }
  }

  f32x4 acc[4][8] = {};
  const char* sA = (const char*)smA;
  const char* sB = (const char*)smB;

  #pragma unroll 1
  for (int kt = 0; kt < 8; ++kt) {
    __syncthreads();
    #pragma unroll
    for (int i = 0; i < 4; ++i) { gl_lds16(pA[i], dA[i]); pA[i] += 64; }
    #pragma unroll
    for (int i = 0; i < 8; ++i) { gl_lds16(pB[i], dB[i]); pB[i] += 64; }
    __syncthreads();
    #pragma unroll
    for (int kbi = 0; kbi < 2; ++kbi) {
      s16x8 af[4], bfr[8];
      #pragma unroll
      for (int mi = 0; mi < 4; ++mi) af[mi]  = *(const s16x8*)(sA + offA[mi][kbi]);
      #pragma unroll
      for (int ni = 0; ni < 8; ++ni) bfr[ni] = *(const s16x8*)(sB + offB[ni][kbi]);
      #pragma unroll
      for (int mi = 0; mi < 4; ++mi)
        #pragma unroll
        for (int ni = 0; ni < 8; ++ni)
          acc[mi][ni] = __builtin_amdgcn_mfma_f32_16x16x32_bf16(af[mi], bfr[ni], acc[mi][ni], 0, 0, 0);
    }
  }

  // -------- epilogue: per-row top2 over this wave's 128 codes, in-register --------
  const int tile = blockIdx.x * 2 + (wave >> 1);
  float resv1 = 0.f, resv2 = 0.f; int resi1 = 0;
  #pragma unroll
  for (int mi = 0; mi < 4; ++mi) {
    #pragma unroll
    for (int r = 0; r < 4; ++r) {
      const int p = mi * 4 + r;
      float v1 = -3.0e38f, v2 = -3.0e38f; int i1 = 0;
      #pragma unroll
      for (int ni = 0; ni < 8; ++ni) {
        float v = acc[mi][ni][r];
        int code = n0 + wave_n + ni * 16 + col;
        if (v > v1) { v2 = v1; v1 = v; i1 = code; }
        else if (v > v2) { v2 = v; }
      }
      #pragma unroll
      for (int off = 1; off < 16; off <<= 1) {   // butterfly over the 16 cols of this quad
        float ov1 = __shfl_xor(v1, off);
        float ov2 = __shfl_xor(v2, off);
        int   oi1 = __shfl_xor(i1, off);
        if (ov1 > v1) { v2 = fmaxf(v1, ov2); v1 = ov1; i1 = oi1; }
        else          { v2 = fmaxf(v2, ov1); }
      }
      if (col == p) { resv1 = v1; resv2 = v2; resi1 = i1; }  // lane-compact
    }
  }
  const int row = wave_m + (col >> 2) * 16 + quad * 4 + (col & 3);  // bijective over 64
  const size_t o = (size_t)(m0 + row) * 64 + tile;                  // token-major
  rv1[o] = resv1;
  rv2[o] = resv2;
  ri1[o] = resi1;
}

// ---------------- K3: exact fp64 rescore -> idx, fused quantized gather + loss + list ----------------
// 256 threads = 4 waves, one token per wave; records token-major (coalesced)
__global__ __launch_bounds__(256) void k_select(const float* __restrict__ x,
                                                const float* __restrict__ wgt,
                                                const float* __restrict__ rv1,
                                                const float* __restrict__ rv2,
                                                const int* __restrict__ ri1,
                                                float* __restrict__ out0,
                                                float* __restrict__ out_idx,
                                                float* __restrict__ lp,
                                                int* __restrict__ cnt,
                                                int* __restrict__ list) {
  const int wave = threadIdx.x >> 6, lane = threadIdx.x & 63;
  const int t = blockIdx.x * 4 + wave;

  const float v1 = rv1[(size_t)t * 64 + lane];
  const float v2 = rv2[(size_t)t * 64 + lane];
  const int   i1 = ri1[(size_t)t * 64 + lane];

  float gm = v1;
  #pragma unroll
  for (int off = 32; off > 0; off >>= 1) gm = fmaxf(gm, __shfl_xor(gm, off));
  const float thresh = gm - MARGIN;

  unsigned long long m1 = __ballot(v1 >= thresh);
  unsigned long long m2 = __ballot(v2 >= thresh);

  const float* xr = x + (size_t)t * DIM + lane * 8;
  float4 x0 = *(const float4*)xr;
  float4 x1 = *(const float4*)(xr + 4);
  double xv[8] = {x0.x, x0.y, x0.z, x0.w, x1.x, x1.y, x1.z, x1.w};

  double bestv = -1e300; int besti = 1 << 30;
  auto evalc = [&](int c) {
    const float* wr = wgt + (size_t)c * DIM + lane * 8;
    float4 w0 = *(const float4*)wr;
    float4 w1 = *(const float4*)(wr + 4);
    double s  = (double)w0.x * xv[0] + (double)w0.y * xv[1] + (double)w0.z * xv[2] + (double)w0.w * xv[3]
              + (double)w1.x * xv[4] + (double)w1.y * xv[5] + (double)w1.z * xv[6] + (double)w1.w * xv[7];
    double nw = (double)w0.x * w0.x + (double)w0.y * w0.y + (double)w0.z * w0.z + (double)w0.w * w0.w
              + (double)w1.x * w1.x + (double)w1.y * w1.y + (double)w1.z * w1.z + (double)w1.w * w1.w;
    #pragma unroll
    for (int off = 1; off < 64; off <<= 1) { s += __shfl_xor(s, off); nw += __shfl_xor(nw, off); }
    double sim = s / sqrt(nw + 1e-12);      // x-norm omitted: constant per token
    if (sim > bestv || (sim == bestv && c < besti)) { bestv = sim; besti = c; }
  };

  while (m1) {
    int b = __builtin_ctzll(m1); m1 &= m1 - 1;
    evalc(__shfl(i1, b));
  }
  while (m2) {                              // rare: second candidate inside same 128-tile
    int b = __builtin_ctzll(m2); m2 &= m2 - 1;
    for (int c0 = 0; c0 < 128; ++c0) evalc(b * 128 + c0);
  }
  if ((unsigned)besti >= KCB) besti = 0;    // hardening: impossible per analysis, fault-proof anyway

  // fused: quantized gather + per-token loss partial
  const float* wr = wgt + (size_t)besti * DIM + lane * 8;
  float4 w0 = *(const float4*)wr;
  float4 w1 = *(const float4*)(wr + 4);
  float* o0 = out0 + (size_t)t * DIM + lane * 8;
  *(float4*)o0 = w0;
  *(float4*)(o0 + 4) = w1;
  double d2 = 0.0;
  double qv[8] = {w0.x, w0.y, w0.z, w0.w, w1.x, w1.y, w1.z, w1.w};
  #pragma unroll
  for (int j = 0; j < 8; ++j) { double d = qv[j] - xv[j]; d2 += d * d; }
  #pragma unroll
  for (int off = 1; off < 64; off <<= 1) d2 += __shfl_xor(d2, off);

  if (lane == 0) {
    lp[t] = (float)d2;
    out_idx[t] = (float)besti;
    int slot = atomicAdd(&cnt[besti], 1);
    if (slot < LISTCAP) list[besti * LISTCAP + slot] = t;
  }
}

// ---------------- K4: scalar reductions (pre-cs, n, loss) ----------------
__global__ __launch_bounds__(256) void k_scalars(const float* __restrict__ cs,
                                                 const int* __restrict__ cnt,
                                                 float* __restrict__ pre,
                                                 const float* __restrict__ lp,
                                                 double* __restrict__ nacc,
                                                 float* __restrict__ out1) {
  __shared__ double red[256];
  const int tid = threadIdx.x;
  double s = 0.0;
  for (int i = tid; i < KCB; i += 256) {
    float p = cs[i] * 0.99f + 0.01f * (float)cnt[i];
    pre[i] = p;
    s += (double)p;
  }
  red[tid] = s; __syncthreads();
  for (int st = 128; st > 0; st >>= 1) { if (tid < st) red[tid] += red[tid + st]; __syncthreads(); }
  if (tid == 0) *nacc = red[0];
  __syncthreads();
  double l = 0.0;
  for (int i = tid; i < NTOK; i += 256) l += (double)lp[i];
  red[tid] = l; __syncthreads();
  for (int st = 128; st > 0; st >>= 1) { if (tid < st) red[tid] += red[tid + st]; __syncthreads(); }
  if (tid == 0) out1[0] = (float)(red[0] / (double)((size_t)NTOK * DIM));
}

// ---------------- K5: per-code gather-sum + EMA finalize (one block per code) ----------------
__global__ __launch_bounds__(256) void k_dw(const float* __restrict__ x,
                                            const float* __restrict__ ema_w,
                                            const int* __restrict__ cnt,
                                            const int* __restrict__ list,
                                            const float* __restrict__ pre,
                                            const double* __restrict__ nacc,
                                            float* __restrict__ out3,
                                            float* __restrict__ out4,
                                            float* __restrict__ out5) {
  const int c = blockIdx.x, tid = threadIdx.x;
  int m = cnt[c]; if (m > LISTCAP) m = LISTCAP;
  const double n = *nacc;
  const float csf = (float)(((double)pre[c] + 1e-5) / (n + (double)KCB * 1e-5) * n);
  const int d0 = tid * 2;
  double s0 = 0.0, s1 = 0.0;
  for (int j = 0; j < m; ++j) {
    int t = list[c * LISTCAP + j] & (NTOK - 1);   // hardening: NTOK is pow2
    float2 v = *(const float2*)(x + (size_t)t * DIM + d0);
    s0 += (double)v.x; s1 += (double)v.y;
  }
  const size_t e = (size_t)c * DIM + d0;
  float n0 = ema_w[e]     * 0.99f + 0.01f * (float)s0;
  float n1 = ema_w[e + 1] * 0.99f + 0.01f * (float)s1;
  out4[e] = n0;       out4[e + 1] = n1;
  out5[e] = n0 / csf; out5[e + 1] = n1 / csf;
  if (tid == 0) out3[c] = csf;
}

// ---------------- launch ----------------
extern "C" void kernel_launch(void* const* d_in, const int* in_sizes, int n_in,
                              void* d_out, int out_size, void* d_ws, size_t ws_size,
                              hipStream_t stream) {
  const float* x    = (const float*)d_in[0];   // [8,2048,512]
  const float* wgt  = (const float*)d_in[1];   // [8192,512]
  const float* cs   = (const float*)d_in[2];   // [8192]
  const float* emaw = (const float*)d_in[3];   // [8192,512]

  char* ws = (char*)d_ws;
  unsigned short* xn  = (unsigned short*)(ws + WS_XN);
  unsigned short* wn  = (unsigned short*)(ws + WS_WN);
  float* rv1   = (float*)(ws + WS_RV1);
  float* rv2   = (float*)(ws + WS_RV2);
  int*   ri1   = (int*)(ws + WS_RI1);
  float* lp    = (float*)(ws + WS_LP);
  float* pre   = (float*)(ws + WS_PRE);
  double* nacc = (double*)(ws + WS_N);
  int*   cnt   = (int*)(ws + WS_CNT);
  int*   list  = (int*)(ws + WS_LIST);

  float* out0 = (float*)d_out;            // quantized_st [8388608]
  float* out1 = out0 + 8388608;           // loss [1]
  float* out2 = out1 + 1;                 // idx  [16384]
  float* out3 = out2 + NTOK;              // new_cs [8192]
  float* out4 = out3 + KCB;               // new_ema_w [4194304]
  float* out5 = out4 + (size_t)KCB * DIM; // new_weight [4194304]

  hipMemsetAsync(cnt, 0, KCB * sizeof(int), stream);

  k_normalize<<<NTOK + KCB, 256, 0, stream>>>(x, wgt, xn, wn);
  k_gemm_top2<<<dim3(32, 128), 256, 0, stream>>>(xn, wn, rv1, rv2, ri1);
  k_select<<<NTOK / 4, 256, 0, stream>>>(x, wgt, rv1, rv2, ri1, out0, out2, lp, cnt, list);
  k_scalars<<<1, 256, 0, stream>>>(cs, cnt, pre, lp, nacc, out1);
  k_dw<<<KCB, 256, 0, stream>>>(x, emaw, cnt, list, pre, nacc, out3, out4, out5);
}

// Round 6
// 369.327 us; speedup vs baseline: 1.8885x; 1.3885x over previous
//
#include <hip/hip_runtime.h>
#include <cstdint>
#include <cstddef>

// ---------------- problem constants ----------------
#define NTOK 16384          // 8*2048 tokens
#define DIM  512
#define KCB  8192           // codebook entries
#define MARGIN 6.0e-3f      // > worst-case bf16 screening error (validated R1-R5)
#define LISTCAP 512         // max tokens per code

typedef short s16x8 __attribute__((ext_vector_type(8)));   // 8 bf16 in 4 VGPRs
typedef float f32x4 __attribute__((ext_vector_type(4)));

// ---------------- workspace layout (bytes) ----------------
static const size_t WS_XN   = 0;           // ushort[NTOK*DIM]   bf16 normalized x  -> 16777216
static const size_t WS_WN   = 16777216;    // ushort[KCB*DIM]    bf16 normalized w  -> 25165824
static const size_t WS_KV   = 25165824;    // uint2[NTOK*64]     packed top2 keys   -> 33554432
static const size_t WS_LP   = 37748736;    // float[NTOK]        loss partials      -> 37814272
static const size_t WS_PRE  = 37814272;    // float[KCB]         pre-smoothing cs   -> 37847040
static const size_t WS_N    = 37847040;    // double             n (256B pad)       -> 37847296
static const size_t WS_CNT  = 37847296;    // int[KCB]           counts (zeroed)    -> 37880064
static const size_t WS_LIST = 37880064;    // int[KCB*LISTCAP]   token lists        -> 54657280

// ---------------- helpers ----------------
__device__ __forceinline__ void gl_lds16(const void* g, void* l) {
  __builtin_amdgcn_global_load_lds(
      (__attribute__((address_space(1))) void*)(uintptr_t)g,
      (__attribute__((address_space(3))) void*)(uint32_t)(uintptr_t)l,
      16, 0, 0);
}

__device__ __forceinline__ unsigned short f2bf(float f) {
  unsigned int u = __float_as_uint(f);
  u = (u + 0x7fffu + ((u >> 16) & 1u)) >> 16;   // RNE
  return (unsigned short)u;
}

// ---------------- K1: l2-normalize x and w rows into bf16 ----------------
__global__ __launch_bounds__(256) void k_normalize(const float* __restrict__ x,
                                                   const float* __restrict__ w,
                                                   unsigned short* __restrict__ xn,
                                                   unsigned short* __restrict__ wn) {
  const int row = blockIdx.x;
  const int tid = threadIdx.x, lane = tid & 63, wave = tid >> 6;
  const float* src;
  unsigned short* dst;
  if (row < NTOK) { src = x + (size_t)row * DIM;          dst = xn + (size_t)row * DIM; }
  else            { src = w + (size_t)(row - NTOK) * DIM; dst = wn + (size_t)(row - NTOK) * DIM; }
  const int e = tid * 2;
  float2 v = *(const float2*)(src + e);
  float ss = v.x * v.x + v.y * v.y;
  #pragma unroll
  for (int off = 32; off > 0; off >>= 1) ss += __shfl_xor(ss, off);
  __shared__ float red[4];
  if (lane == 0) red[wave] = ss;
  __syncthreads();
  const float s = red[0] + red[1] + red[2] + red[3];
  const float inv = rsqrtf(s + 1e-12f);
  unsigned int lo = f2bf(v.x * inv), hi = f2bf(v.y * inv);
  *(unsigned int*)(dst + e) = lo | (hi << 16);
}

// ---------------- K2: bf16 MFMA GEMM, block 128m x 256n, wave 64m x 128n ----------------
// packed-key epilogue: key = (bits(sim+2.0) & ~0x7F) | (in-tile code 0..127)
// record = uint2{k1,k2} at kv[t*64 + tile], token-major
__global__ __launch_bounds__(256, 2) void k_gemm_top2(const unsigned short* __restrict__ xn,
                                                      const unsigned short* __restrict__ wn,
                                                      uint2* __restrict__ kv) {
  __shared__ __align__(16) unsigned short smA[128 * 64];   // 16 KB
  __shared__ __align__(16) unsigned short smB[256 * 64];   // 32 KB
  const int tid = threadIdx.x, wave = tid >> 6, lane = tid & 63;
  const int quad = lane >> 4, col = lane & 15;
  const int wave_m = (wave & 1) * 64, wave_n = (wave >> 1) * 128;
  const int n0 = blockIdx.x * 256, m0 = blockIdx.y * 128;

  const unsigned short* pA[4];
  const unsigned short* pB[8];
  unsigned short* dA[4];
  unsigned short* dB[8];
  #pragma unroll
  for (int i = 0; i < 4; ++i) {
    int s = wave * 256 + i * 64 + lane;
    int row = s >> 3, cg = (s & 7) ^ (row & 7);
    pA[i] = xn + (size_t)(m0 + row) * DIM + cg * 8;
    dA[i] = &smA[(size_t)(wave * 256 + i * 64) * 8];
  }
  #pragma unroll
  for (int i = 0; i < 8; ++i) {
    int s = wave * 512 + i * 64 + lane;
    int row = s >> 3, cg = (s & 7) ^ (row & 7);
    pB[i] = wn + (size_t)(n0 + row) * DIM + cg * 8;
    dB[i] = &smB[(size_t)(wave * 512 + i * 64) * 8];
  }

  int offA[4][2], offB[8][2];
  #pragma unroll
  for (int kbi = 0; kbi < 2; ++kbi) {
    int kb = kbi * 4 + quad;
    #pragma unroll
    for (int mi = 0; mi < 4; ++mi) {
      int row = wave_m + mi * 16 + col;
      offA[mi][kbi] = (row * 8 + (kb ^ (row & 7))) * 16;
    }
    #pragma unroll
    for (int ni = 0; ni < 8; ++ni) {
      int row = wave_n + ni * 16 + col;
      offB[ni][kbi] = (row * 8 + (kb ^ (row & 7))) * 16;
    }
  }

  f32x4 acc[4][8] = {};
  const char* sA = (const char*)smA;
  const char* sB = (const char*)smB;

  #pragma unroll 1
  for (int kt = 0; kt < 8; ++kt) {
    __syncthreads();
    #pragma unroll
    for (int i = 0; i < 4; ++i) { gl_lds16(pA[i], dA[i]); pA[i] += 64; }
    #pragma unroll
    for (int i = 0; i < 8; ++i) { gl_lds16(pB[i], dB[i]); pB[i] += 64; }
    __syncthreads();
    #pragma unroll
    for (int kbi = 0; kbi < 2; ++kbi) {
      s16x8 af[4], bfr[8];
      #pragma unroll
      for (int mi = 0; mi < 4; ++mi) af[mi]  = *(const s16x8*)(sA + offA[mi][kbi]);
      #pragma unroll
      for (int ni = 0; ni < 8; ++ni) bfr[ni] = *(const s16x8*)(sB + offB[ni][kbi]);
      #pragma unroll
      for (int mi = 0; mi < 4; ++mi)
        #pragma unroll
        for (int ni = 0; ni < 8; ++ni)
          acc[mi][ni] = __builtin_amdgcn_mfma_f32_16x16x32_bf16(af[mi], bfr[ni], acc[mi][ni], 0, 0, 0);
    }
  }

  // -------- epilogue: packed-key top2 over this wave's 128 codes --------
  const int tile = blockIdx.x * 2 + (wave >> 1);
  unsigned int rk1 = 0, rk2 = 0;
  #pragma unroll
  for (int mi = 0; mi < 4; ++mi) {
    #pragma unroll
    for (int r = 0; r < 4; ++r) {
      const int p = mi * 4 + r;
      unsigned int k1 = 0, k2 = 0;
      #pragma unroll
      for (int ni = 0; ni < 8; ++ni) {
        float vb = acc[mi][ni][r] + 2.0f;                 // biased positive -> uint order == float order
        unsigned int key = (__float_as_uint(vb) & ~0x7Fu) | (unsigned int)(ni * 16 + col);
        unsigned int mn = min(k1, key);
        k1 = max(k1, key);
        k2 = max(k2, mn);
      }
      #pragma unroll
      for (int off = 1; off < 16; off <<= 1) {
        unsigned int o1 = (unsigned int)__shfl_xor((int)k1, off);
        unsigned int o2 = (unsigned int)__shfl_xor((int)k2, off);
        unsigned int mn = min(k1, o1);
        k1 = max(k1, o1);
        k2 = max(max(k2, o2), mn);
      }
      if (col == p) { rk1 = k1; rk2 = k2; }               // lane-compact
    }
  }
  const int row = wave_m + (col >> 2) * 16 + quad * 4 + (col & 3);  // bijective over 64
  kv[(size_t)(m0 + row) * 64 + tile] = make_uint2(rk1, rk2);
}

// ---------------- K3: exact fp64 rescore -> idx, fused gather + loss + list ----------------
// 256 threads = 4 waves, one token per wave
__global__ __launch_bounds__(256) void k_select(const float* __restrict__ x,
                                                const float* __restrict__ wgt,
                                                const uint2* __restrict__ kv,
                                                float* __restrict__ out0,
                                                float* __restrict__ out_idx,
                                                float* __restrict__ lp,
                                                int* __restrict__ cnt,
                                                int* __restrict__ list) {
  const int wave = threadIdx.x >> 6, lane = threadIdx.x & 63;
  const int t = blockIdx.x * 4 + wave;

  const uint2 kp = kv[(size_t)t * 64 + lane];
  const float v1 = __uint_as_float(kp.x);     // biased (+2.0), index bits add <=3e-5
  const float v2 = __uint_as_float(kp.y);
  const int   i1 = lane * 128 + (int)(kp.x & 0x7Fu);

  float gm = v1;
  #pragma unroll
  for (int off = 32; off > 0; off >>= 1) gm = fmaxf(gm, __shfl_xor(gm, off));
  const float thresh = gm - MARGIN;

  unsigned long long m1 = __ballot(v1 >= thresh);
  unsigned long long m2 = __ballot(v2 >= thresh);

  const float* xrow = x + (size_t)t * DIM;
  const float* xr = xrow + lane * 8;
  float4 x0 = *(const float4*)xr;
  float4 x1 = *(const float4*)(xr + 4);
  double xv[8] = {x0.x, x0.y, x0.z, x0.w, x1.x, x1.y, x1.z, x1.w};

  double bestv = -1e300; int besti = 1 << 30;   // per-lane running best

  // wave-collective exact eval (result uniform across lanes)
  auto evalc = [&](int c) {
    const float* wr = wgt + (size_t)c * DIM + lane * 8;
    float4 w0 = *(const float4*)wr;
    float4 w1 = *(const float4*)(wr + 4);
    double s  = (double)w0.x * xv[0] + (double)w0.y * xv[1] + (double)w0.z * xv[2] + (double)w0.w * xv[3]
              + (double)w1.x * xv[4] + (double)w1.y * xv[5] + (double)w1.z * xv[6] + (double)w1.w * xv[7];
    double nw = (double)w0.x * w0.x + (double)w0.y * w0.y + (double)w0.z * w0.z + (double)w0.w * w0.w
              + (double)w1.x * w1.x + (double)w1.y * w1.y + (double)w1.z * w1.z + (double)w1.w * w1.w;
    #pragma unroll
    for (int off = 1; off < 64; off <<= 1) { s += __shfl_xor(s, off); nw += __shfl_xor(nw, off); }
    double sim = s / sqrt(nw + 1e-12);      // x-norm omitted: constant per token
    if (sim > bestv || (sim == bestv && c < besti)) { bestv = sim; besti = c; }
  };

  while (m1) {
    int b = __builtin_ctzll(m1); m1 &= m1 - 1;
    evalc(__shfl(i1, b));
  }
  // lane-parallel full-tile rescan (tile with 2+ candidates): 2 chunks of 64 codes
  while (m2) {
    int b = __builtin_ctzll(m2); m2 &= m2 - 1;
    #pragma unroll 1
    for (int chunk = 0; chunk < 2; ++chunk) {
      const int c = b * 128 + chunk * 64 + lane;
      const float* wr = wgt + (size_t)c * DIM;
      double s = 0.0, nw = 0.0;
      #pragma unroll 4
      for (int d = 0; d < DIM; d += 4) {
        float4 wv = *(const float4*)(wr + d);
        float4 xw = *(const float4*)(xrow + d);   // lane-uniform broadcast
        s  += (double)wv.x * xw.x + (double)wv.y * xw.y + (double)wv.z * xw.z + (double)wv.w * xw.w;
        nw += (double)wv.x * wv.x + (double)wv.y * wv.y + (double)wv.z * wv.z + (double)wv.w * wv.w;
      }
      double sim = s / sqrt(nw + 1e-12);
      if (sim > bestv || (sim == bestv && c < besti)) { bestv = sim; besti = c; }
    }
  }
  // wave argmax (tie -> smallest index)
  #pragma unroll
  for (int off = 1; off < 64; off <<= 1) {
    double ov = __shfl_xor(bestv, off);
    int    oi = __shfl_xor(besti, off);
    if (ov > bestv || (ov == bestv && oi < besti)) { bestv = ov; besti = oi; }
  }
  if ((unsigned)besti >= KCB) besti = 0;    // hardening

  // fused: quantized gather + per-token loss partial
  const float* wr = wgt + (size_t)besti * DIM + lane * 8;
  float4 w0 = *(const float4*)wr;
  float4 w1 = *(const float4*)(wr + 4);
  float* o0 = out0 + (size_t)t * DIM + lane * 8;
  *(float4*)o0 = w0;
  *(float4*)(o0 + 4) = w1;
  double d2 = 0.0;
  double qv[8] = {w0.x, w0.y, w0.z, w0.w, w1.x, w1.y, w1.z, w1.w};
  #pragma unroll
  for (int j = 0; j < 8; ++j) { double d = qv[j] - xv[j]; d2 += d * d; }
  #pragma unroll
  for (int off = 1; off < 64; off <<= 1) d2 += __shfl_xor(d2, off);

  if (lane == 0) {
    lp[t] = (float)d2;
    out_idx[t] = (float)besti;
    int slot = atomicAdd(&cnt[besti], 1);
    if (slot < LISTCAP) list[besti * LISTCAP + slot] = t;
  }
}

// ---------------- K4: scalar reductions (pre-cs, n, loss) ----------------
__global__ __launch_bounds__(256) void k_scalars(const float* __restrict__ cs,
                                                 const int* __restrict__ cnt,
                                                 float* __restrict__ pre,
                                                 const float* __restrict__ lp,
                                                 double* __restrict__ nacc,
                                                 float* __restrict__ out1) {
  __shared__ double red[256];
  const int tid = threadIdx.x;
  double s = 0.0;
  for (int i = tid * 4; i < KCB; i += 1024) {
    float4 c4 = *(const float4*)(cs + i);
    int4   n4 = *(const int4*)(cnt + i);
    float p0 = c4.x * 0.99f + 0.01f * (float)n4.x;
    float p1 = c4.y * 0.99f + 0.01f * (float)n4.y;
    float p2 = c4.z * 0.99f + 0.01f * (float)n4.z;
    float p3 = c4.w * 0.99f + 0.01f * (float)n4.w;
    *(float4*)(pre + i) = make_float4(p0, p1, p2, p3);
    s += (double)p0 + (double)p1 + (double)p2 + (double)p3;
  }
  red[tid] = s; __syncthreads();
  for (int st = 128; st > 0; st >>= 1) { if (tid < st) red[tid] += red[tid + st]; __syncthreads(); }
  if (tid == 0) *nacc = red[0];
  __syncthreads();
  double l = 0.0;
  for (int i = tid * 4; i < NTOK; i += 1024) {
    float4 l4 = *(const float4*)(lp + i);
    l += (double)l4.x + (double)l4.y + (double)l4.z + (double)l4.w;
  }
  red[tid] = l; __syncthreads();
  for (int st = 128; st > 0; st >>= 1) { if (tid < st) red[tid] += red[tid + st]; __syncthreads(); }
  if (tid == 0) out1[0] = (float)(red[0] / (double)((size_t)NTOK * DIM));
}

// ---------------- K5: per-code gather-sum + EMA finalize (one block per code) ----------------
__global__ __launch_bounds__(256) void k_dw(const float* __restrict__ x,
                                            const float* __restrict__ ema_w,
                                            const int* __restrict__ cnt,
                                            const int* __restrict__ list,
                                            const float* __restrict__ pre,
                                            const double* __restrict__ nacc,
                                            float* __restrict__ out3,
                                            float* __restrict__ out4,
                                            float* __restrict__ out5) {
  const int c = blockIdx.x, tid = threadIdx.x;
  int m = cnt[c]; if (m > LISTCAP) m = LISTCAP;
  const double n = *nacc;
  const float csf = (float)(((double)pre[c] + 1e-5) / (n + (double)KCB * 1e-5) * n);
  const int d0 = tid * 2;
  double s0 = 0.0, s1 = 0.0;
  for (int j = 0; j < m; ++j) {
    int t = list[c * LISTCAP + j] & (NTOK - 1);
    float2 v = *(const float2*)(x + (size_t)t * DIM + d0);
    s0 += (double)v.x; s1 += (double)v.y;
  }
  const size_t e = (size_t)c * DIM + d0;
  float n0 = ema_w[e]     * 0.99f + 0.01f * (float)s0;
  float n1 = ema_w[e + 1] * 0.99f + 0.01f * (float)s1;
  out4[e] = n0;       out4[e + 1] = n1;
  out5[e] = n0 / csf; out5[e + 1] = n1 / csf;
  if (tid == 0) out3[c] = csf;
}

// ---------------- launch ----------------
extern "C" void kernel_launch(void* const* d_in, const int* in_sizes, int n_in,
                              void* d_out, int out_size, void* d_ws, size_t ws_size,
                              hipStream_t stream) {
  const float* x    = (const float*)d_in[0];   // [8,2048,512]
  const float* wgt  = (const float*)d_in[1];   // [8192,512]
  const float* cs   = (const float*)d_in[2];   // [8192]
  const float* emaw = (const float*)d_in[3];   // [8192,512]

  char* ws = (char*)d_ws;
  unsigned short* xn  = (unsigned short*)(ws + WS_XN);
  unsigned short* wn  = (unsigned short*)(ws + WS_WN);
  uint2* kv    = (uint2*)(ws + WS_KV);
  float* lp    = (float*)(ws + WS_LP);
  float* pre   = (float*)(ws + WS_PRE);
  double* nacc = (double*)(ws + WS_N);
  int*   cnt   = (int*)(ws + WS_CNT);
  int*   list  = (int*)(ws + WS_LIST);

  float* out0 = (float*)d_out;            // quantized_st [8388608]
  float* out1 = out0 + 8388608;           // loss [1]
  float* out2 = out1 + 1;                 // idx  [16384]
  float* out3 = out2 + NTOK;              // new_cs [8192]
  float* out4 = out3 + KCB;               // new_ema_w [4194304]
  float* out5 = out4 + (size_t)KCB * DIM; // new_weight [4194304]

  hipMemsetAsync(cnt, 0, KCB * sizeof(int), stream);

  k_normalize<<<NTOK + KCB, 256, 0, stream>>>(x, wgt, xn, wn);
  k_gemm_top2<<<dim3(32, 128), 256, 0, stream>>>(xn, wn, kv);
  k_select<<<NTOK / 4, 256, 0, stream>>>(x, wgt, kv, out0, out2, lp, cnt, list);
  k_scalars<<<1, 256, 0, stream>>>(cs, cnt, pre, lp, nacc, out1);
  k_dw<<<KCB, 256, 0, stream>>>(x, emaw, cnt, list, pre, nacc, out3, out4, out5);
}